// Round 13
// baseline (320.757 us; speedup 1.0000x reference)
//
#include <hip/hip_runtime.h>
#include <cmath>

#define BB 2
#define AA 5
#define CH 64
#define HH 128
#define WW 128
#define HW (HH*WW)
#define NIMG (BB*AA)
#define NPTS 209   // 19x11 gather points per tile

typedef __attribute__((ext_vector_type(8))) _Float16 half8;
typedef __attribute__((ext_vector_type(4))) float floatx4;
typedef unsigned int uint32;

__device__ inline half8 hzero() {
    half8 v;
#pragma unroll
    for (int e = 0; e < 8; ++e) v[e] = (_Float16)0.f;
    return v;
}

__device__ inline float fsigmoid(float x) {
    return __builtin_amdgcn_rcpf(1.f + __builtin_amdgcn_exp2f(-1.442695041f * x));
}
__device__ inline float ftanh(float x) {
    return 2.f * fsigmoid(2.f * x) - 1.f;
}

// ---------------------------------------------------------------------------
// prep: fused to_nhwc + pack_w + COORD PRECOMPUTE (one launch).
// blocks 0..5119:    feats fp32 planar -> NHWC f16 [NIMG,HW,64]
// blocks 5120..5227: wx -> f16 B-fragment layout
// blocks 5228..9407: gather-coord records. The bilinear coord/clamp/weight
//   chain depends only on (trans,i,j,tile,pt) — identical for BOTH fused
//   iterations and for all 8 octet lanes. Computed once here (verbatim
//   v13 math), stored as 32-B records: 4 element-offsets + 4 f32 weights.
//   Invalid points: offsets 0, weights 0 (blend yields exact 0).
// ---------------------------------------------------------------------------
__global__ __launch_bounds__(256) void prep_kernel(
    const float* __restrict__ feats, const float* __restrict__ wx,
    const float* __restrict__ trans,
    _Float16* __restrict__ dst, half8* __restrict__ wp,
    uint32* __restrict__ coords)
{
    const int bid = blockIdx.x;
    if (bid < 5120) {
        const int img = bid >> 9;
        const int inner = bid & 511;
        const int cg  = inner & 7;
        const int pb  = inner >> 3;
        const int p   = pb * 256 + threadIdx.x;
        const float* s = feats + ((size_t)img * CH + cg * 8) * HW + p;
        half8 v;
#pragma unroll
        for (int e = 0; e < 8; ++e) v[e] = (_Float16)s[e * HW];
        *(half8*)(dst + ((size_t)img * HW + p) * 64 + cg * 8) = v;
    } else if (bid < 5228) {
        int idx = (bid - 5120) * 256 + threadIdx.x;   // 4*9*4*192 = 27648
        if (idx >= 4 * 9 * 4 * 192) return;
        int oc = idx % 192; int r = idx / 192;
        int gk = r & 3; r >>= 2; int tap = r % 9; int cc = r / 9;
        int ky = tap / 3, kx = tap % 3;
        half8 v;
#pragma unroll
        for (int e = 0; e < 8; ++e)
            v[e] = (_Float16)wx[(((size_t)oc * 128 + cc * 32 + gk * 8 + e) * 3 + ky) * 3 + kx];
        wp[idx] = v;
    } else {
        // coord records: cidx = ((bi*4 + jj)*128 + tile)*209 + pt
        const int cidx = (bid - 5228) * 256 + threadIdx.x;   // 1,070,080 exactly
        const int pt   = cidx % NPTS;
        int r          = cidx / NPTS;        // 0..5119
        const int tile = r & 127;
        r >>= 7;                             // 0..39
        const int jj   = r & 3;
        const int bi   = r >> 2;             // 0..9
        const int b = bi / AA, i = bi % AA;
        const int j = jj + (jj >= i ? 1 : 0);   // jj-th element of {0..4}\{i}, ascending

        const float* t = trans + (((size_t)b * AA + i) * AA + j) * 16;
        const float t00 = t[0], t01 = t[1], t03 = t[3];
        const float t10 = t[4], t11 = t[5], t13 = t[7];
        const float dxs = 2.f * t03;
        const float dys = -2.f * t13;
        const float sxf = floorf(dxs), syf = floorf(dys);
        const int sx = (int)sxf, sy = (int)syf;
        const float Cx = (0.5f - 64.f) * (t00 + t01) + 63.5f;
        const float Cy = (0.5f - 64.f) * (t10 + t11) + 63.5f;

        const int x0 = (tile & 7) * 16;
        const int y0 = (tile >> 3) * 8;
        const int prow = pt / 19;
        const int pcol = pt - prow * 19;
        const int qx = x0 - 1 + sx + pcol;
        const int qy = y0 - 1 + sy + prow;

        uint32 o00 = 0, o01 = 0, o10 = 0, o11 = 0;
        float w00 = 0.f, w01 = 0.f, w10 = 0.f, w11 = 0.f;
        if (((unsigned)qx < (unsigned)WW) & ((unsigned)qy < (unsigned)HH)) {
            const float px = t00 * (float)qx + t01 * (float)qy + Cx;
            const float py = t10 * (float)qx + t11 * (float)qy + Cy;
            const float x0f = floorf(px), y0f = floorf(py);
            const int ix0 = (int)x0f, iy0 = (int)y0f;
            const float wx1 = px - x0f, wx0 = 1.f - wx1;
            const float wy1 = py - y0f, wy0 = 1.f - wy1;
            const bool vx0 = (ix0 >= 0) & (ix0 < WW);
            const bool vx1 = (ix0 + 1 >= 0) & (ix0 + 1 < WW);
            const bool vy0 = (iy0 >= 0) & (iy0 < HH);
            const bool vy1 = (iy0 + 1 >= 0) & (iy0 + 1 < HH);
            const int cx0 = min(max(ix0, 0), WW - 1);
            const int cx1 = min(max(ix0 + 1, 0), WW - 1);
            const int cy0 = min(max(iy0, 0), HH - 1);
            const int cy1 = min(max(iy0 + 1, 0), HH - 1);
            w00 = (vx0 & vy0) ? wx0 * wy0 : 0.f;
            w01 = (vx1 & vy0) ? wx1 * wy0 : 0.f;
            w10 = (vx0 & vy1) ? wx0 * wy1 : 0.f;
            w11 = (vx1 & vy1) ? wx1 * wy1 : 0.f;
            const int r0 = cy0 * WW, r1 = cy1 * WW;
            o00 = (uint32)((r0 + cx0) * 64);
            o01 = (uint32)((r0 + cx1) * 64);
            o10 = (uint32)((r1 + cx0) * 64);
            o11 = (uint32)((r1 + cx1) * 64);
        }
        uint32* cp = coords + (size_t)cidx * 8;
        cp[0] = o00; cp[1] = o01; cp[2] = o10; cp[3] = o11;
        cp[4] = __builtin_bit_cast(uint32, w00);
        cp[5] = __builtin_bit_cast(uint32, w01);
        cp[6] = __builtin_bit_cast(uint32, w10);
        cp[7] = __builtin_bit_cast(uint32, w11);
    }
}

// ---------------------------------------------------------------------------
// v19 = v13 with phase B's inline coord chain replaced by a precomputed
// global record read. Phase structure, barriers, f_lds flow, and blend
// arithmetic are byte-identical to v13 (the passing kernel). The three
// prior correctness failures all restructured INTRA-kernel dataflow; this
// uses only the inter-kernel global-memory path already proven by
// wpack/B1/B2. 8 octet lanes read the same 32-B record -> HW broadcast.
// ---------------------------------------------------------------------------
#define APL2 180   // g-plane stride in half8 units (10*18)

__global__ __launch_bounds__(512, 4) void fused_warp_conv(
    const _Float16* __restrict__ in,    // [NIMG, HW, 64] prev feats (f16)
    const float* __restrict__ trans,    // [B, A, A, 4, 4]
    const uint32* __restrict__ coords,  // [(bi*4+jj)*128+tile][209][8]
    const half8* __restrict__ wp,       // packed weights [36][768]
    const float* __restrict__ bx,       // [192]
    const float* __restrict__ bh,       // [192]
    float* __restrict__ out_f32,        // [NIMG,64,H,W] or null
    _Float16* __restrict__ out_f16)     // [NIMG,HW,64] or null
{
    __shared__ half8 lds_in[16 * APL2];   // 46080 B: 16 ch-octet planes x 10x18
    __shared__ half8 f_lds[NPTS * 8];     // 26752 B: 19x11 gather pts x 8 octets

    const int tid = threadIdx.x;
    const int bi  = blockIdx.z;
    const int b   = bi / AA, i = bi % AA;
    const int x0 = (blockIdx.x & 7) * 16;       // 8 x-tiles
    const int y0 = (blockIdx.x >> 3) * 8;       // 16 y-tiles

    // conv roles
    const int w   = tid >> 6;                   // wave 0..7
    const int wo  = w & 3;                      // oc-group
    const int wh  = w >> 2;                     // y-half
    const int ln  = tid & 15;
    const int kq  = (tid & 63) >> 4;
    // gather roles
    const int slc = tid & 7;                    // ch octet
    const int ptb = tid >> 3;                   // 0..63 point slot

    // ---- phase 0: direct halo ch0..63 -> planes 0..7 ----
    const _Float16* inimg = in + (size_t)bi * HW * 64;
    for (int f = tid; f < 1440; f += 512) {
        const int g = f / 180; const int r = f % 180;
        const int row = r / 18; const int col = r % 18;
        const int y = y0 + row - 1, x = x0 + col - 1;
        half8 v = hzero();
        if ((unsigned)x < (unsigned)WW && (unsigned)y < (unsigned)HH)
            v = *(const half8*)(inimg + ((size_t)y * WW + x) * 64 + g * 8);
        lds_in[g * APL2 + r] = v;
    }

    // ---- phase 1: warp-mean over j != i for the 18x10 halo ----
    half8 macc[3];
#pragma unroll
    for (int k2 = 0; k2 < 3; ++k2) macc[k2] = hzero();

    int jj = 0;
    for (int j = 0; j < AA; ++j) {
        if (j == i) continue;
        const float* t = trans + (((size_t)b * AA + i) * AA + j) * 16;
        const float t03 = t[3], t13 = t[7];
        const float dxs = 2.f * t03;
        const float dys = -2.f * t13;
        const float fx = dxs - floorf(dxs);
        const float fy = dys - floorf(dys);
        const _Float16* srcj = in + (size_t)(b * AA + j) * HW * 64 + slc * 8;
        const uint32* cbase = coords
            + (((size_t)(bi * 4 + jj) * 128 + blockIdx.x) * NPTS) * 8;

        __syncthreads();   // f_lds free of previous j's readers
#pragma unroll
        for (int it = 0; it < 4; ++it) {
            const int pt = it * 64 + ptb;
            if (pt < NPTS) {
                const uint32* cp = cbase + pt * 8;
                const uint32 o00 = cp[0], o01 = cp[1], o10 = cp[2], o11 = cp[3];
                const float w00 = __builtin_bit_cast(float, cp[4]);
                const float w01 = __builtin_bit_cast(float, cp[5]);
                const float w10 = __builtin_bit_cast(float, cp[6]);
                const float w11 = __builtin_bit_cast(float, cp[7]);
                const half8 A  = *(const half8*)(srcj + o00);
                const half8 Bv = *(const half8*)(srcj + o01);
                const half8 Cv = *(const half8*)(srcj + o10);
                const half8 D  = *(const half8*)(srcj + o11);
                // packed f16 blend: v_pk_fma_f16 — identical arithmetic to v13
                const half8 ev = A  * (half8)(_Float16)w00 + Bv * (half8)(_Float16)w01
                               + Cv * (half8)(_Float16)w10 + D  * (half8)(_Float16)w11;
                f_lds[pt * 8 + slc] = ev;
            }
        }
        __syncthreads();   // staging visible

        const half8 wA8 = (half8)(_Float16)((1.f - fx) * (1.f - fy));
        const half8 wB8 = (half8)(_Float16)(fx * (1.f - fy));
        const half8 wC8 = (half8)(_Float16)((1.f - fx) * fy);
        const half8 wD8 = (half8)(_Float16)(fx * fy);
#pragma unroll
        for (int k2 = 0; k2 < 3; ++k2) {
            const int item = tid + 512 * k2;
            if (item < 1440) {
                const int px = item >> 3, g = item & 7;
                const int row = px / 18, col = px - row * 18;
                const half8* fp = &f_lds[(row * 19 + col) * 8 + g];
                macc[k2] += fp[0] * wA8 + fp[8] * wB8 + fp[152] * wC8 + fp[160] * wD8;
            }
        }
        ++jj;
    }

    // mean -> planes 8..15 (zero outside image, matching old bounds check)
    {
        const half8 q8 = (half8)(_Float16)0.25f;   // 1/(A-1)
#pragma unroll
        for (int k2 = 0; k2 < 3; ++k2) {
            const int item = tid + 512 * k2;
            if (item < 1440) {
                const int px = item >> 3, g = item & 7;
                const int row = px / 18, col = px - row * 18;
                const int y = y0 + row - 1, x = x0 + col - 1;
                half8 v = hzero();
                if ((unsigned)x < (unsigned)WW && (unsigned)y < (unsigned)HH)
                    v = macc[k2] * q8;
                lds_in[(8 + g) * APL2 + row * 18 + col] = v;
            }
        }
    }

    floatx4 acc[4][3];     // [y-row][gate]
#pragma unroll
    for (int s = 0; s < 4; ++s)
#pragma unroll
        for (int t = 0; t < 3; ++t)
#pragma unroll
            for (int r = 0; r < 4; ++r) acc[s][t][r] = 0.f;

    __syncthreads();

    // ---- phase 2: verified barrier-free K-loop, depth-2 b prefetch ----
    const half8* wbase = wp + kq * 192 + wo * 16 + ln;
    half8 bp0[3], bp1[3];
#pragma unroll
    for (int t = 0; t < 3; ++t) bp0[t] = wbase[t * 64];
#pragma unroll
    for (int t = 0; t < 3; ++t) bp1[t] = wbase[768 + t * 64];

#pragma unroll
    for (int s = 0; s < 36; ++s) {
        const int cc = s / 9, tap = s - cc * 9;
        const int dy = tap / 3, dx = tap - dy * 3;
        half8 bcur[3];
#pragma unroll
        for (int t = 0; t < 3; ++t) { bcur[t] = bp0[t]; bp0[t] = bp1[t]; }
        if (s + 2 < 36) {
            const half8* wsrc = wbase + (size_t)(s + 2) * 768;
#pragma unroll
            for (int t = 0; t < 3; ++t) bp1[t] = wsrc[t * 64];
        }
        half8 a[4];
#pragma unroll
        for (int t = 0; t < 4; ++t)
            a[t] = lds_in[(cc * 4 + kq) * APL2 + (wh * 4 + t + dy) * 18 + ln + dx];
#pragma unroll
        for (int t = 0; t < 4; ++t)
#pragma unroll
            for (int u = 0; u < 3; ++u)
                acc[t][u] = __builtin_amdgcn_mfma_f32_16x16x32_f16(a[t], bcur[u], acc[t][u], 0, 0, 0);
    }

    // epilogue: GRU gating. D layout: col(oc%16)=ln, row(x)=kq*4+reg.
    const int c = wo * 16 + ln;                 // 0..63
    const float bxr = bx[c] + bh[c];
    const float bxz = bx[64 + c] + bh[64 + c];
    const float bxn = bx[128 + c];
    const float bnn = bh[128 + c];
#pragma unroll
    for (int s = 0; s < 4; ++s) {
        const int y = y0 + wh * 4 + s;
#pragma unroll
        for (int reg = 0; reg < 4; ++reg) {
            const int x = x0 + kq * 4 + reg;
            const float xr = acc[s][0][reg] + bxr;
            const float xz = acc[s][1][reg] + bxz;
            const float xn = acc[s][2][reg] + bxn;
            const float rg = fsigmoid(xr);
            const float zg = fsigmoid(xz);
            const float n  = ftanh(xn + rg * bnn);
            const float h  = (1.f - zg) * n;
            if (out_f32)
                out_f32[((size_t)bi * CH + c) * HW + y * WW + x] = h;
            else
                out_f16[((size_t)bi * HW + y * WW + x) * 64 + c] = (_Float16)h;
        }
    }
}

// ---------------------------------------------------------------------------
extern "C" void kernel_launch(void* const* d_in, const int* in_sizes, int n_in,
                              void* d_out, int out_size, void* d_ws, size_t ws_size,
                              hipStream_t stream) {
    const float* feats = (const float*)d_in[0];
    const float* trans = (const float*)d_in[1];
    const float* wx    = (const float*)d_in[2];
    // d_in[3] = wh (unused: h0 = 0)
    const float* bx    = (const float*)d_in[4];
    const float* bh    = (const float*)d_in[5];
    float* out = (float*)d_out;

    char* ws = (char*)d_ws;
    half8*    wpack = (half8*)ws;                              // 442,368 B
    _Float16* B1 = (_Float16*)(ws + 442368);                   // 21.0 MB
    _Float16* B2 = (_Float16*)(ws + 442368 + (size_t)NIMG * HW * 64 * 2);
    uint32* coords = (uint32*)(ws + 442368 + 2 * (size_t)NIMG * HW * 64 * 2);
    // coords: 10*4*128*209 records x 32 B = 34.2 MB; total ws ~76.6 MB

    prep_kernel<<<9408, 256, 0, stream>>>(feats, wx, trans, B1, wpack, coords);

    dim3 fgrid(128, 1, NIMG);      // 16x8 px tiles, 512 threads

    // iteration 1
    fused_warp_conv<<<fgrid, 512, 0, stream>>>(B1, trans, coords, wpack, bx, bh, nullptr, B2);
    // iteration 2
    fused_warp_conv<<<fgrid, 512, 0, stream>>>(B2, trans, coords, wpack, bx, bh, out, nullptr);
}

// Round 14
// 297.456 us; speedup vs baseline: 1.0783x; 1.0783x over previous
//
#include <hip/hip_runtime.h>
#include <cmath>

#define BB 2
#define AA 5
#define CH 64
#define HH 128
#define WW 128
#define HW (HH*WW)
#define NIMG (BB*AA)

typedef __attribute__((ext_vector_type(8))) _Float16 half8;
typedef __attribute__((ext_vector_type(4))) float floatx4;
typedef unsigned int uint32;

__device__ inline half8 hzero() {
    half8 v;
#pragma unroll
    for (int e = 0; e < 8; ++e) v[e] = (_Float16)0.f;
    return v;
}

__device__ inline float fsigmoid(float x) {
    return __builtin_amdgcn_rcpf(1.f + __builtin_amdgcn_exp2f(-1.442695041f * x));
}
__device__ inline float ftanh(float x) {
    return 2.f * fsigmoid(2.f * x) - 1.f;
}

// ---------------------------------------------------------------------------
// prep: fused to_nhwc + pack_w (one launch).
// blocks 0..5119: feats fp32 planar [NIMG,64,H,W] -> NHWC f16 [NIMG,HW,64]
// blocks 5120..5227: wx [192,128,3,3] fp32 -> f16 B-fragment layout
// ---------------------------------------------------------------------------
__global__ __launch_bounds__(256) void prep_kernel(
    const float* __restrict__ feats, const float* __restrict__ wx,
    _Float16* __restrict__ dst, half8* __restrict__ wp)
{
    const int bid = blockIdx.x;
    if (bid < 5120) {
        const int img = bid >> 9;
        const int inner = bid & 511;
        const int cg  = inner & 7;
        const int pb  = inner >> 3;
        const int p   = pb * 256 + threadIdx.x;
        const float* s = feats + ((size_t)img * CH + cg * 8) * HW + p;
        half8 v;
#pragma unroll
        for (int e = 0; e < 8; ++e) v[e] = (_Float16)s[e * HW];
        *(half8*)(dst + ((size_t)img * HW + p) * 64 + cg * 8) = v;
    } else {
        int idx = (bid - 5120) * 256 + threadIdx.x;   // 4*9*4*192 = 27648
        if (idx >= 4 * 9 * 4 * 192) return;
        int oc = idx % 192; int r = idx / 192;
        int gk = r & 3; r >>= 2; int tap = r % 9; int cc = r / 9;
        int ky = tap / 3, kx = tap % 3;
        half8 v;
#pragma unroll
        for (int e = 0; e < 8; ++e)
            v[e] = (_Float16)wx[(((size_t)oc * 128 + cc * 32 + gk * 8 + e) * 3 + ky) * 3 + kx];
        wp[idx] = v;
    }
}

// ---------------------------------------------------------------------------
// FINAL: v13 verbatim — the best harness-verified kernel (293.4 µs at R6;
// 302.5 at R12 re-measure; ~3% cross-run noise band).
//
// Session ledger (from 332.7 µs baseline):
//  WIN  fuse warp_mean into conv (one kernel, no 20 MB mean round-trip,
//       64-ch NHWC records)                              ~ -16 µs
//  WIN  gather VALU-thinning: packed-f16 corner blend (v_pk_fma_f16) +
//       affine coord simplification (2 FMA/coord)        ~ -19 µs
//  WIN  prep launch fusion (to_nhwc + pack_w)            ~ -3 µs
//  NULL conv tile shape / occupancy / forced pipeline / source sched
//       (4 experiments; conv K-loop pinned at ~44% of f16 MFMA ceiling —
//       the simple-schedule structural plateau)
//  NULL/NEG XCD swizzle, s_setprio, global-precomputed coords (latency-
//       chained gather: VALU cuts below the latency floor don't pay)
//  FAIL x3 (undiagnosed corruption) j-loop restructures: coord dedup via
//       LDS x2, feats-K interleave — needs on-box .s debugging; closed.
//
// Not a HW roofline (MfmaUtil ~30%, HBM ~10%): a structural plateau of
// this decomposition. Remaining theoretical headroom ~15-20 µs sits
// behind the corrupting j-loop restructure frontier.
// ---------------------------------------------------------------------------
#define APL2 180   // g-plane stride in half8 units (10*18)

__global__ __launch_bounds__(512, 4) void fused_warp_conv(
    const _Float16* __restrict__ in,    // [NIMG, HW, 64] prev feats (f16)
    const float* __restrict__ trans,    // [B, A, A, 4, 4]
    const half8* __restrict__ wp,       // packed weights [36][768]
    const float* __restrict__ bx,       // [192]
    const float* __restrict__ bh,       // [192]
    float* __restrict__ out_f32,        // [NIMG,64,H,W] or null
    _Float16* __restrict__ out_f16)     // [NIMG,HW,64] or null
{
    __shared__ half8 lds_in[16 * APL2];   // 46080 B: 16 ch-octet planes x 10x18
    __shared__ half8 f_lds[209 * 8];      // 26752 B: 19x11 gather pts x 8 octets

    const int tid = threadIdx.x;
    const int bi  = blockIdx.z;
    const int b   = bi / AA, i = bi % AA;
    const int x0 = (blockIdx.x & 7) * 16;       // 8 x-tiles
    const int y0 = (blockIdx.x >> 3) * 8;       // 16 y-tiles

    // conv roles
    const int w   = tid >> 6;                   // wave 0..7
    const int wo  = w & 3;                      // oc-group
    const int wh  = w >> 2;                     // y-half
    const int ln  = tid & 15;
    const int kq  = (tid & 63) >> 4;
    // gather roles
    const int slc = tid & 7;                    // ch octet
    const int ptb = tid >> 3;                   // 0..63 point slot

    // ---- phase 0: direct halo ch0..63 -> planes 0..7 ----
    const _Float16* inimg = in + (size_t)bi * HW * 64;
    for (int f = tid; f < 1440; f += 512) {
        const int g = f / 180; const int r = f % 180;
        const int row = r / 18; const int col = r % 18;
        const int y = y0 + row - 1, x = x0 + col - 1;
        half8 v = hzero();
        if ((unsigned)x < (unsigned)WW && (unsigned)y < (unsigned)HH)
            v = *(const half8*)(inimg + ((size_t)y * WW + x) * 64 + g * 8);
        lds_in[g * APL2 + r] = v;
    }

    // ---- phase 1: warp-mean over j != i for the 18x10 halo ----
    half8 macc[3];
#pragma unroll
    for (int k2 = 0; k2 < 3; ++k2) macc[k2] = hzero();

    for (int j = 0; j < AA; ++j) {
        if (j == i) continue;
        const float* t = trans + (((size_t)b * AA + i) * AA + j) * 16;
        const float t00 = t[0], t01 = t[1], t03 = t[3];
        const float t10 = t[4], t11 = t[5], t13 = t[7];
        const float dxs = 2.f * t03;
        const float dys = -2.f * t13;
        const float sxf = floorf(dxs), syf = floorf(dys);
        const int sx = (int)sxf, sy = (int)syf;
        const float fx = dxs - sxf, fy = dys - syf;
        // px = t00*qx + t01*qy + Cx  (exact algebra of the normalized form)
        const float Cx = (0.5f - 64.f) * (t00 + t01) + 63.5f;
        const float Cy = (0.5f - 64.f) * (t10 + t11) + 63.5f;
        const _Float16* srcj = in + (size_t)(b * AA + j) * HW * 64 + slc * 8;

        __syncthreads();   // f_lds free of previous j's readers
#pragma unroll
        for (int it = 0; it < 4; ++it) {
            const int pt = it * 64 + ptb;
            if (pt < 209) {
                const int prow = pt / 19;
                const int pcol = pt - prow * 19;
                const int qx = x0 - 1 + sx + pcol;
                const int qy = y0 - 1 + sy + prow;
                half8 ev = hzero();
                if (((unsigned)qx < (unsigned)WW) & ((unsigned)qy < (unsigned)HH)) {
                    const float px = t00 * (float)qx + t01 * (float)qy + Cx;
                    const float py = t10 * (float)qx + t11 * (float)qy + Cy;
                    const float x0f = floorf(px), y0f = floorf(py);
                    const int ix0 = (int)x0f, iy0 = (int)y0f;
                    const float wx1 = px - x0f, wx0 = 1.f - wx1;
                    const float wy1 = py - y0f, wy0 = 1.f - wy1;
                    const bool vx0 = (ix0 >= 0) & (ix0 < WW);
                    const bool vx1 = (ix0 + 1 >= 0) & (ix0 + 1 < WW);
                    const bool vy0 = (iy0 >= 0) & (iy0 < HH);
                    const bool vy1 = (iy0 + 1 >= 0) & (iy0 + 1 < HH);
                    const int cx0 = min(max(ix0, 0), WW - 1);
                    const int cx1 = min(max(ix0 + 1, 0), WW - 1);
                    const int cy0 = min(max(iy0, 0), HH - 1);
                    const int cy1 = min(max(iy0 + 1, 0), HH - 1);
                    const float w00 = (vx0 & vy0) ? wx0 * wy0 : 0.f;
                    const float w01 = (vx1 & vy0) ? wx1 * wy0 : 0.f;
                    const float w10 = (vx0 & vy1) ? wx0 * wy1 : 0.f;
                    const float w11 = (vx1 & vy1) ? wx1 * wy1 : 0.f;
                    const half8 A  = *(const half8*)(srcj + ((size_t)cy0 * WW + cx0) * 64);
                    const half8 Bv = *(const half8*)(srcj + ((size_t)cy0 * WW + cx1) * 64);
                    const half8 Cv = *(const half8*)(srcj + ((size_t)cy1 * WW + cx0) * 64);
                    const half8 D  = *(const half8*)(srcj + ((size_t)cy1 * WW + cx1) * 64);
                    // packed f16 blend: v_pk_fma_f16, no cvt chain
                    ev = A  * (half8)(_Float16)w00 + Bv * (half8)(_Float16)w01
                       + Cv * (half8)(_Float16)w10 + D  * (half8)(_Float16)w11;
                }
                f_lds[pt * 8 + slc] = ev;
            }
        }
        __syncthreads();   // staging visible

        const half8 wA8 = (half8)(_Float16)((1.f - fx) * (1.f - fy));
        const half8 wB8 = (half8)(_Float16)(fx * (1.f - fy));
        const half8 wC8 = (half8)(_Float16)((1.f - fx) * fy);
        const half8 wD8 = (half8)(_Float16)(fx * fy);
#pragma unroll
        for (int k2 = 0; k2 < 3; ++k2) {
            const int item = tid + 512 * k2;
            if (item < 1440) {
                const int px = item >> 3, g = item & 7;
                const int row = px / 18, col = px - row * 18;
                const half8* fp = &f_lds[(row * 19 + col) * 8 + g];
                macc[k2] += fp[0] * wA8 + fp[8] * wB8 + fp[152] * wC8 + fp[160] * wD8;
            }
        }
    }

    // mean -> planes 8..15 (zero outside image, matching old bounds check)
    {
        const half8 q8 = (half8)(_Float16)0.25f;   // 1/(A-1)
#pragma unroll
        for (int k2 = 0; k2 < 3; ++k2) {
            const int item = tid + 512 * k2;
            if (item < 1440) {
                const int px = item >> 3, g = item & 7;
                const int row = px / 18, col = px - row * 18;
                const int y = y0 + row - 1, x = x0 + col - 1;
                half8 v = hzero();
                if ((unsigned)x < (unsigned)WW && (unsigned)y < (unsigned)HH)
                    v = macc[k2] * q8;
                lds_in[(8 + g) * APL2 + row * 18 + col] = v;
            }
        }
    }

    floatx4 acc[4][3];     // [y-row][gate]
#pragma unroll
    for (int s = 0; s < 4; ++s)
#pragma unroll
        for (int t = 0; t < 3; ++t)
#pragma unroll
            for (int r = 0; r < 4; ++r) acc[s][t][r] = 0.f;

    __syncthreads();

    // ---- phase 2: verified barrier-free K-loop, depth-2 b prefetch ----
    const half8* wbase = wp + kq * 192 + wo * 16 + ln;
    half8 bp0[3], bp1[3];
#pragma unroll
    for (int t = 0; t < 3; ++t) bp0[t] = wbase[t * 64];
#pragma unroll
    for (int t = 0; t < 3; ++t) bp1[t] = wbase[768 + t * 64];

#pragma unroll
    for (int s = 0; s < 36; ++s) {
        const int cc = s / 9, tap = s - cc * 9;
        const int dy = tap / 3, dx = tap - dy * 3;
        half8 bcur[3];
#pragma unroll
        for (int t = 0; t < 3; ++t) { bcur[t] = bp0[t]; bp0[t] = bp1[t]; }
        if (s + 2 < 36) {
            const half8* wsrc = wbase + (size_t)(s + 2) * 768;
#pragma unroll
            for (int t = 0; t < 3; ++t) bp1[t] = wsrc[t * 64];
        }
        half8 a[4];
#pragma unroll
        for (int t = 0; t < 4; ++t)
            a[t] = lds_in[(cc * 4 + kq) * APL2 + (wh * 4 + t + dy) * 18 + ln + dx];
#pragma unroll
        for (int t = 0; t < 4; ++t)
#pragma unroll
            for (int u = 0; u < 3; ++u)
                acc[t][u] = __builtin_amdgcn_mfma_f32_16x16x32_f16(a[t], bcur[u], acc[t][u], 0, 0, 0);
    }

    // epilogue: GRU gating. D layout: col(oc%16)=ln, row(x)=kq*4+reg.
    const int c = wo * 16 + ln;                 // 0..63
    const float bxr = bx[c] + bh[c];
    const float bxz = bx[64 + c] + bh[64 + c];
    const float bxn = bx[128 + c];
    const float bnn = bh[128 + c];
#pragma unroll
    for (int s = 0; s < 4; ++s) {
        const int y = y0 + wh * 4 + s;
#pragma unroll
        for (int reg = 0; reg < 4; ++reg) {
            const int x = x0 + kq * 4 + reg;
            const float xr = acc[s][0][reg] + bxr;
            const float xz = acc[s][1][reg] + bxz;
            const float xn = acc[s][2][reg] + bxn;
            const float rg = fsigmoid(xr);
            const float zg = fsigmoid(xz);
            const float n  = ftanh(xn + rg * bnn);
            const float h  = (1.f - zg) * n;
            if (out_f32)
                out_f32[((size_t)bi * CH + c) * HW + y * WW + x] = h;
            else
                out_f16[((size_t)bi * HW + y * WW + x) * 64 + c] = (_Float16)h;
        }
    }
}

// ---------------------------------------------------------------------------
extern "C" void kernel_launch(void* const* d_in, const int* in_sizes, int n_in,
                              void* d_out, int out_size, void* d_ws, size_t ws_size,
                              hipStream_t stream) {
    const float* feats = (const float*)d_in[0];
    const float* trans = (const float*)d_in[1];
    const float* wx    = (const float*)d_in[2];
    // d_in[3] = wh (unused: h0 = 0)
    const float* bx    = (const float*)d_in[4];
    const float* bh    = (const float*)d_in[5];
    float* out = (float*)d_out;

    char* ws = (char*)d_ws;
    half8*    wpack = (half8*)ws;                              // 442,368 B
    _Float16* B1 = (_Float16*)(ws + 442368);                   // 21 MB NHWC-64 f16
    _Float16* B2 = (_Float16*)(ws + 442368 + (size_t)NIMG * HW * 64 * 2);

    prep_kernel<<<5228, 256, 0, stream>>>(feats, wx, B1, wpack);

    dim3 fgrid(128, 1, NIMG);      // 16x8 px tiles, 512 threads

    // iteration 1
    fused_warp_conv<<<fgrid, 512, 0, stream>>>(B1, trans, wpack, bx, bh, nullptr, B2);
    // iteration 2
    fused_warp_conv<<<fgrid, 512, 0, stream>>>(B2, trans, wpack, bx, bh, out, nullptr);
}